// Round 16
// baseline (316.470 us; speedup 1.0000x reference)
//
#include <hip/hip_runtime.h>
#include <stdint.h>

typedef __attribute__((ext_vector_type(8))) __bf16 bf16x8;
typedef __attribute__((ext_vector_type(4))) float f32x4;
typedef __attribute__((ext_vector_type(8))) int i32x8;

#define DEV __device__ __forceinline__

DEV unsigned short f2bf(float f) {
  union { float f; uint32_t u; } v; v.f = f;
  return (unsigned short)((v.u + 0x7fffu + ((v.u >> 16) & 1u)) >> 16);
}

// pack two fp32 -> bf16 pair (round-half-up) in one v_perm (stable absmax floor)
DEV uint32_t pk2bf(float lo, float hi) {
  union { float f; uint32_t u; } a, b;
  a.f = lo; b.f = hi;
  return __builtin_amdgcn_perm(b.u + 0x8000u, a.u + 0x8000u, 0x07060302u);
}

DEV void gld16(const void* g, void* l) {
  __builtin_amdgcn_global_load_lds(
      (const __attribute__((address_space(1))) uint32_t*)g,
      (__attribute__((address_space(3))) uint32_t*)l, 16, 0, 0);
}

union Frag8 { i32x8 v; uint4 q[2]; };

// ---------------- convert x fp32 -> fp8 e4m3 (8 elems/thread) ----------------
__global__ __launch_bounds__(256) void k_cvt_x(const float* __restrict__ x,
                                               uint8_t* __restrict__ x8) {
  size_t t = (size_t)blockIdx.x * 256 + threadIdx.x;
  const float4* xv = (const float4*)x;
  float4 a = xv[t * 2], b = xv[t * 2 + 1];
  int lo = 0, hi = 0;
  lo = __builtin_amdgcn_cvt_pk_fp8_f32(a.x, a.y, lo, false);
  lo = __builtin_amdgcn_cvt_pk_fp8_f32(a.z, a.w, lo, true);
  hi = __builtin_amdgcn_cvt_pk_fp8_f32(b.x, b.y, hi, false);
  hi = __builtin_amdgcn_cvt_pk_fp8_f32(b.z, b.w, hi, true);
  int2 pk; pk.x = lo; pk.y = hi;
  *(int2*)&x8[t * 8] = pk;
}

// -------- weights: W[k][n] fp32 -> z<3: fp8 Wt[n][k] (x32); z=3: bf16 Wt[n][k] --------
__global__ void k_cvt_w(const float* __restrict__ W0, const float* __restrict__ W1,
                        const float* __restrict__ W2, const float* __restrict__ W3,
                        uint8_t* __restrict__ W8, unsigned short* __restrict__ WoT) {
  const int z = blockIdx.z;
  const float* W = (z == 0) ? W0 : (z == 1) ? W1 : (z == 2) ? W2 : W3;
  __shared__ float tile[32][33];
  const int n0 = blockIdx.x * 32, k0 = blockIdx.y * 32;
  const int tx = threadIdx.x, ty = threadIdx.y;
  const int tid = ty * 32 + tx;
#pragma unroll
  for (int i = 0; i < 4; i++)
    tile[ty * 4 + i][tx] = W[(size_t)(k0 + ty * 4 + i) * 1024 + n0 + tx];
  __syncthreads();
  if (z < 3) {
    int nn = tid >> 3, kg = tid & 7;  // tile[kk][nn] = W[k0+kk][n0+nn]
    int w_ = 0;
    w_ = __builtin_amdgcn_cvt_pk_fp8_f32(32.f * tile[kg * 4 + 0][nn],
                                         32.f * tile[kg * 4 + 1][nn], w_, false);
    w_ = __builtin_amdgcn_cvt_pk_fp8_f32(32.f * tile[kg * 4 + 2][nn],
                                         32.f * tile[kg * 4 + 3][nn], w_, true);
    *(uint32_t*)&W8[(size_t)z * 1048576 + (size_t)(n0 + nn) * 1024 + k0 + kg * 4] =
        (uint32_t)w_;
  } else {
#pragma unroll
    for (int i = 0; i < 4; i++)
      WoT[(size_t)(n0 + ty * 4 + i) * 1024 + k0 + tx] = f2bf(tile[tx][ty * 4 + i]);
  }
}

// ------- QKV projection: MX-fp8 128x128 tile, BK=128, K=1024, fused pool -------
// Single-barrier pipelined K-loop: prefetch issued AFTER the ready barrier (all
// waves provably done reading the target buffer by program order), waited by
// vmcnt(0) at the next step. 1 barrier/step. + T5 setprio.
// z=0 -> Qp [bh][s2][d] PRE-SCALED by 0.125*log2(e), z=1 -> Kp, z=2 -> Vt [bh][d][s2]
__global__ __launch_bounds__(256) void k_gemm_qkv(
    const uint8_t* __restrict__ A, const uint8_t* __restrict__ W8,
    const float* __restrict__ bq, const float* __restrict__ bk,
    const float* __restrict__ bv,
    unsigned short* __restrict__ Qp, unsigned short* __restrict__ Kp,
    unsigned short* __restrict__ Vt) {
  const int tid = threadIdx.x;
  int flat = (blockIdx.z * 128 + blockIdx.y) * 8 + blockIdx.x;
  int swz = (flat & 7) * 384 + (flat >> 3);   // XCD x owns swz in [x*384,(x+1)*384)
  const int n0 = (swz & 7) * 128;
  const int m0 = ((swz >> 3) & 127) * 128;
  const int z = swz >> 10;
  const uint8_t* Bt = W8 + (size_t)z * 1048576;
  const float* bias = (z == 0) ? bq : (z == 1) ? bk : bv;

  __shared__ __align__(16) uint8_t lA[2][16384];
  __shared__ __align__(16) uint8_t lB[2][16384];

  const int lane = tid & 63, w = tid >> 6;
  const int wr = w >> 1, wc = w & 1;
  const int r = lane & 15, qd = lane >> 4;
  const int rl = lane >> 3, sg = lane & 7;

  f32x4 acc[4][4];
#pragma unroll
  for (int i = 0; i < 4; i++)
#pragma unroll
    for (int j = 0; j < 4; j++) acc[i][j] = (f32x4){0.f, 0.f, 0.f, 0.f};

  // hoisted staging addresses (loop-invariant; K-offset folds into imm)
  const uint8_t* gA[4]; const uint8_t* gB[4]; uint32_t lo[4];
#pragma unroll
  for (int p = 0; p < 4; p++) {
    int row = (p * 4 + w) * 8 + rl;
    int g = sg ^ (row & 7);  // 16B-granule XOR swizzle (pre-swizzled global src)
    gA[p] = A + (size_t)(m0 + row) * 1024 + g * 16;
    gB[p] = Bt + (size_t)(n0 + row) * 1024 + g * 16;
    lo[p] = row * 128 + sg * 16;
  }

  // prologue: issue tile-0 loads into buffer 0
#pragma unroll
  for (int p = 0; p < 4; p++) {
    gld16(gA[p], &lA[0][lo[p]]);
    gld16(gB[p], &lB[0][lo[p]]);
  }

#pragma unroll
  for (int t = 0; t < 8; t++) {
    const int cb = t & 1;
    // tile t's loads are the only outstanding vmem ops
    asm volatile("s_waitcnt vmcnt(0)" ::: "memory");
    __builtin_amdgcn_s_barrier();   // tile t visible; all waves done reading cb^1
    // issue next tile's loads into cb^1 (safe: see barrier argument above)
    if (t < 7) {
#pragma unroll
      for (int p = 0; p < 4; p++) {
        gld16(gA[p] + (t + 1) * 128, &lA[cb ^ 1][lo[p]]);
        gld16(gB[p] + (t + 1) * 128, &lB[cb ^ 1][lo[p]]);
      }
      __builtin_amdgcn_sched_barrier(0);  // pin issue ahead of compute
    }
    // compute current buffer (loads for t+1 in flight underneath)
    __builtin_amdgcn_s_setprio(1);
    const uint8_t* lAc = lA[cb];
    const uint8_t* lBc = lB[cb];
    Frag8 bfr[4];
#pragma unroll
    for (int nt = 0; nt < 4; nt++) {
      int row = wc * 64 + nt * 16 + r;
      int g0 = (2 * qd) ^ (row & 7), g1 = (2 * qd + 1) ^ (row & 7);
      bfr[nt].q[0] = *(const uint4*)&lBc[row * 128 + g0 * 16];
      bfr[nt].q[1] = *(const uint4*)&lBc[row * 128 + g1 * 16];
    }
#pragma unroll
    for (int mt = 0; mt < 4; mt++) {
      int row = wr * 64 + mt * 16 + r;
      int g0 = (2 * qd) ^ (row & 7), g1 = (2 * qd + 1) ^ (row & 7);
      Frag8 af;
      af.q[0] = *(const uint4*)&lAc[row * 128 + g0 * 16];
      af.q[1] = *(const uint4*)&lAc[row * 128 + g1 * 16];
#pragma unroll
      for (int nt = 0; nt < 4; nt++)
        acc[mt][nt] = __builtin_amdgcn_mfma_scale_f32_16x16x128_f8f6f4(
            af.v, bfr[nt].v, acc[mt][nt], 0, 0, 0, 0x7f7f7f7f, 0, 0x7f7f7f7f);
    }
    __builtin_amdgcn_s_setprio(0);
  }

  unsigned short* OP = (z == 0) ? Qp : Kp;
  // fold softmax scale 0.125*log2(e) into Q (z==0); -0.5 shift dropped (cancels)
  const float K2 = 0.125f * 1.44269504f;
  const float osc = (z == 0) ? 0.03125f * K2 : 0.03125f;   // undo W x32, maybe *K2
  const float bsc = (z == 0) ? K2 : 1.f;
#pragma unroll
  for (int nt = 0; nt < 4; nt++) {
    int n = n0 + wc * 64 + nt * 16 + r;
    float bv_ = bias[n] * bsc;
    int h = n >> 6, d = n & 63;
#pragma unroll
    for (int mt = 0; mt < 4; mt++) {
      int mg = m0 + wr * 64 + mt * 16 + qd * 4;
      int b = mg >> 12, s2 = (mg & 4095) >> 1;
      int bh = b * 16 + h;
      f32x4 a = acc[mt][nt];
      float v0 = fmaxf(a.x, a.y) * osc + bv_;
      float v1 = fmaxf(a.z, a.w) * osc + bv_;
      if (z == 2) {
        uint32_t pk = (uint32_t)f2bf(v0) | ((uint32_t)f2bf(v1) << 16);
        *(uint32_t*)&Vt[((size_t)bh * 64 + d) * 2048 + s2] = pk;  // s2 even
      } else {
        size_t base = ((size_t)bh * 2048 + s2) * 64 + d;
        OP[base] = f2bf(v0);
        OP[base + 64] = f2bf(v1);
      }
    }
  }
}

// ---------------- final GEMM: out = Am(bf16) @ WoT^T + bo, fp32 out ----------------
// BM=32 tile (1024 blocks, 4/CU) + single-barrier pipelined K-loop + setprio.
__global__ __launch_bounds__(256) void k_gemm_out(
    const unsigned short* __restrict__ A, const unsigned short* __restrict__ Bt,
    const float* __restrict__ bias, float* __restrict__ fout) {
  const int tid = threadIdx.x;
  int flat = blockIdx.y * 8 + blockIdx.x;      // 1024 blocks = 8 XCDs x 128
  int swz = (flat & 7) * 128 + (flat >> 3);
  const int n0 = (swz & 7) * 128, m0 = (swz >> 3) * 32;

  __shared__ __align__(16) unsigned short lA[2][2048];   // 32 x 64
  __shared__ __align__(16) unsigned short lB[2][8192];   // 128 x 64

  const int lane = tid & 63, w = tid >> 6;
  const int wr = w >> 1, wc = w & 1;           // wave tile: 16 m x 64 n
  const int r = lane & 15, qd = lane >> 4;
  const int srow = tid >> 3, sg = tid & 7;     // srow 0..31

  f32x4 acc[4];
#pragma unroll
  for (int j = 0; j < 4; j++) acc[j] = (f32x4){0.f, 0.f, 0.f, 0.f};

  const unsigned short* gA; uint32_t loA;
  const unsigned short* gB[4]; uint32_t loB[4];
  {
    int row = srow;
    int gs = sg ^ (row & 7);
    gA = A + (size_t)(m0 + row) * 1024 + gs * 8;
    loA = row * 64 + sg * 8;
  }
#pragma unroll
  for (int p = 0; p < 4; p++) {
    int row = p * 32 + srow;
    int gs = sg ^ (row & 7);
    gB[p] = Bt + (size_t)(n0 + row) * 1024 + gs * 8;
    loB[p] = row * 64 + sg * 8;
  }

  gld16(gA, &lA[0][loA]);
#pragma unroll
  for (int p = 0; p < 4; p++) gld16(gB[p], &lB[0][loB[p]]);

#pragma unroll
  for (int t = 0; t < 16; t++) {
    const int cb = t & 1;
    asm volatile("s_waitcnt vmcnt(0)" ::: "memory");
    __builtin_amdgcn_s_barrier();
    if (t < 15) {
      gld16(gA + (t + 1) * 64, &lA[cb ^ 1][loA]);
#pragma unroll
      for (int p = 0; p < 4; p++) gld16(gB[p] + (t + 1) * 64, &lB[cb ^ 1][loB[p]]);
      __builtin_amdgcn_sched_barrier(0);
    }
    __builtin_amdgcn_s_setprio(1);
    const unsigned short* lAc = lA[cb];
    const unsigned short* lBc = lB[cb];
#pragma unroll
    for (int kf = 0; kf < 2; kf++) {
      bf16x8 af, bfr[4];
      {
        int row = wr * 16 + r;
        int lg = (kf * 4 + qd) ^ (row & 7);
        af = *(const bf16x8*)&lAc[row * 64 + lg * 8];
      }
#pragma unroll
      for (int nt = 0; nt < 4; nt++) {
        int row = wc * 64 + nt * 16 + r;
        int lg = (kf * 4 + qd) ^ (row & 7);
        bfr[nt] = *(const bf16x8*)&lBc[row * 64 + lg * 8];
      }
#pragma unroll
      for (int nt = 0; nt < 4; nt++)
        acc[nt] = __builtin_amdgcn_mfma_f32_16x16x32_bf16(af, bfr[nt],
                                                          acc[nt], 0, 0, 0);
    }
    __builtin_amdgcn_s_setprio(0);
  }

#pragma unroll
  for (int nt = 0; nt < 4; nt++) {
    int n = n0 + wc * 64 + nt * 16 + r;
    float bv = bias[n];
    int mg = m0 + wr * 16 + qd * 4;
    f32x4 a = acc[nt];
    fout[(size_t)(mg + 0) * 1024 + n] = a.x + bv;
    fout[(size_t)(mg + 1) * 1024 + n] = a.y + bv;
    fout[(size_t)(mg + 2) * 1024 + n] = a.z + bv;
    fout[(size_t)(mg + 3) * 1024 + n] = a.w + bv;
  }
}

// ---------------- flash attention (no-max softmax) + fused q-maxpool ----------------
// 8 warps x 32 q-rows (QBLK=256, R15-verified) + single-barrier pipelined K/V loop.
// pk2bf (stable), T5 setprio.
__global__ __launch_bounds__(512) void k_attn(const unsigned short* __restrict__ Qp,
                                              const unsigned short* __restrict__ Kp,
                                              const unsigned short* __restrict__ Vt,
                                              unsigned short* __restrict__ Am) {
  const int tid = threadIdx.x;
  int flat = blockIdx.y * 8 + blockIdx.x;      // 512 blocks = 8 XCDs x 64
  int swz = (flat & 7) * 64 + (flat >> 3);
  const int qt = swz & 7, bh = swz >> 3;
  const int w = tid >> 6, lane = tid & 63;
  const int r = lane & 15, qd = lane >> 4;
  const int srow = tid >> 3, sg = tid & 7;     // srow 0..63

  __shared__ __align__(16) unsigned short lK[2][4096];
  __shared__ __align__(16) unsigned short lV[2][4096];
  __shared__ __align__(16) unsigned short lP[8][2][1280];

  const int q0 = qt * 256;
  const size_t qbase = ((size_t)bh * 2048 + q0 + w * 32 + r) * 64;
  bf16x8 bq0[2], bq1[2];
  bq0[0] = *(const bf16x8*)&Qp[qbase + qd * 8];
  bq1[0] = *(const bf16x8*)&Qp[qbase + 32 + qd * 8];
  bq0[1] = *(const bf16x8*)&Qp[qbase + 1024 + qd * 8];        // +16 q-rows
  bq1[1] = *(const bf16x8*)&Qp[qbase + 1024 + 32 + qd * 8];

  union { bf16x8 v; unsigned short u[8]; } onef;
#pragma unroll
  for (int j = 0; j < 8; j++) onef.u[j] = 0x3F80;  // bf16 1.0

  const unsigned short* Kg = Kp + (size_t)bh * 2048 * 64;
  const unsigned short* Vg = Vt + (size_t)bh * 64 * 2048;

  f32x4 accO[2][4]; f32x4 accS[2];
#pragma unroll
  for (int h = 0; h < 2; h++) {
    accS[h] = (f32x4){0.f, 0.f, 0.f, 0.f};
#pragma unroll
    for (int i = 0; i < 4; i++) accO[h][i] = (f32x4){0.f, 0.f, 0.f, 0.f};
  }

  char* lPw[2] = {(char*)&lP[w][0][0], (char*)&lP[w][1][0]};

  // hoisted staging addresses (64 rows covered by 512 threads: 1 K + 1 V each)
  const unsigned short* gK; const unsigned short* gV; uint32_t loKV;
  {
    int row = srow;
    int gs = sg ^ (row & 7);
    gK = Kg + (size_t)row * 64 + gs * 8;
    gV = Vg + (size_t)row * 2048 + gs * 8;
    loKV = row * 64 + sg * 8;
  }

  // prologue: issue K/V tile 0 into buffer 0
  gld16(gK, &lK[0][loKV]);
  gld16(gV, &lV[0][loKV]);

  for (int kb2 = 0; kb2 < 2048; kb2 += 128) {
#pragma unroll
    for (int ph = 0; ph < 2; ph++) {
      const int cb = ph;
      const int kn = kb2 + ph * 64 + 64;
      asm volatile("s_waitcnt vmcnt(0)" ::: "memory");
      __builtin_amdgcn_s_barrier();   // tile ready; all waves done reading cb^1
      // issue next K/V tile into cb^1 (race-free by barrier argument)
      if (kn < 2048) {
        gld16(gK + (size_t)kn * 64, &lK[cb ^ 1][loKV]);
        gld16(gV + kn, &lV[cb ^ 1][loKV]);
        __builtin_amdgcn_sched_barrier(0);
      }

      const unsigned short* lKc = lK[cb];
      const unsigned short* lVc = lV[cb];

      // QK^T: read each K fragment ONCE, use for both q-halves
      __builtin_amdgcn_s_setprio(1);
      f32x4 s[2][4];
#pragma unroll
      for (int mt = 0; mt < 4; mt++) {
        int row = mt * 16 + r;
        int lg0 = qd ^ (row & 7), lg1 = (4 + qd) ^ (row & 7);
        bf16x8 ak0 = *(const bf16x8*)&lKc[row * 64 + lg0 * 8];
        bf16x8 ak1 = *(const bf16x8*)&lKc[row * 64 + lg1 * 8];
        f32x4 zz = (f32x4){0.f, 0.f, 0.f, 0.f};
        s[0][mt] = __builtin_amdgcn_mfma_f32_16x16x32_bf16(
            ak1, bq1[0],
            __builtin_amdgcn_mfma_f32_16x16x32_bf16(ak0, bq0[0], zz, 0, 0, 0),
            0, 0, 0);
        s[1][mt] = __builtin_amdgcn_mfma_f32_16x16x32_bf16(
            ak1, bq1[1],
            __builtin_amdgcn_mfma_f32_16x16x32_bf16(ak0, bq0[1], zz, 0, 0, 0),
            0, 0, 0);
      }
      __builtin_amdgcn_s_setprio(0);

      // p = exp2(s) (scale pre-folded into Q); pack via pk2bf (round-half-up)
#pragma unroll
      for (int h = 0; h < 2; h++)
#pragma unroll
        for (int mt = 0; mt < 4; mt++) {
          float p0 = __builtin_amdgcn_exp2f(s[h][mt][0]);
          float p1 = __builtin_amdgcn_exp2f(s[h][mt][1]);
          float p2 = __builtin_amdgcn_exp2f(s[h][mt][2]);
          float p3 = __builtin_amdgcn_exp2f(s[h][mt][3]);
          uint2 dw; dw.x = pk2bf(p0, p1); dw.y = pk2bf(p2, p3);
          int off = r * 160 + (((2 * mt + (qd >> 1)) ^ (r & 7)) << 4) + ((qd & 1) << 3);
          *(uint2*)(lPw[h] + off) = dw;
        }

      bf16x8 ap0[2], ap1[2];
      __builtin_amdgcn_s_setprio(1);
#pragma unroll
      for (int h = 0; h < 2; h++) {
        ap0[h] = *(const bf16x8*)(lPw[h] + r * 160 + ((qd ^ (r & 7)) << 4));
        ap1[h] = *(const bf16x8*)(lPw[h] + r * 160 + (((4 + qd) ^ (r & 7)) << 4));
        // row-sum on the matrix pipe (same C layout as accO)
        accS[h] = __builtin_amdgcn_mfma_f32_16x16x32_bf16(ap0[h], onef.v, accS[h], 0, 0, 0);
        accS[h] = __builtin_amdgcn_mfma_f32_16x16x32_bf16(ap1[h], onef.v, accS[h], 0, 0, 0);
      }

      // PV: read each V fragment ONCE, use for both q-halves
#pragma unroll
      for (int nt = 0; nt < 4; nt++) {
        int row = nt * 16 + r;
        int lg0 = qd ^ (row & 7), lg1 = (4 + qd) ^ (row & 7);
        bf16x8 bv0 = *(const bf16x8*)&lVc[row * 64 + lg0 * 8];
        bf16x8 bv1 = *(const bf16x8*)&lVc[row * 64 + lg1 * 8];
#pragma unroll
        for (int h = 0; h < 2; h++) {
          accO[h][nt] = __builtin_amdgcn_mfma_f32_16x16x32_bf16(ap0[h], bv0,
                                                               accO[h][nt], 0, 0, 0);
          accO[h][nt] = __builtin_amdgcn_mfma_f32_16x16x32_bf16(ap1[h], bv1,
                                                               accO[h][nt], 0, 0, 0);
        }
      }
      __builtin_amdgcn_s_setprio(0);
    }
  }

  // epilogue: divide by row-sums (accS has identical lane layout to accO) + q-maxpool
#pragma unroll
  for (int h = 0; h < 2; h++) {
    float i0 = 1.f / accS[h][0], i1 = 1.f / accS[h][1];
    float i2 = 1.f / accS[h][2], i3 = 1.f / accS[h][3];
    int q = q0 + w * 32 + h * 16 + qd * 4;
    int s4 = q >> 1;
#pragma unroll
    for (int nt = 0; nt < 4; nt++) {
      int d = nt * 16 + r;
      float o0 = fmaxf(accO[h][nt][0] * i0, accO[h][nt][1] * i1);
      float o1 = fmaxf(accO[h][nt][2] * i2, accO[h][nt][3] * i3);
      size_t base = ((size_t)bh * 1024 + s4) * 64 + d;
      Am[base] = f2bf(o0);
      Am[base + 64] = f2bf(o1);
    }
  }
}

extern "C" void kernel_launch(void* const* d_in, const int* in_sizes, int n_in,
                              void* d_out, int out_size, void* d_ws, size_t ws_size,
                              hipStream_t stream) {
  const float* x  = (const float*)d_in[0];
  const float* Wq = (const float*)d_in[1];
  const float* bq = (const float*)d_in[2];
  const float* Wk = (const float*)d_in[3];
  const float* bk = (const float*)d_in[4];
  const float* Wv = (const float*)d_in[5];
  const float* bv = (const float*)d_in[6];
  const float* Wo = (const float*)d_in[7];
  const float* bo = (const float*)d_in[8];
  float* out = (float*)d_out;

  uint8_t* ws = (uint8_t*)d_ws;
  uint8_t*        x8  = ws;                                  // 16,777,216 B
  uint8_t*        W8  = ws + 16777216;                       //  3,145,728 B
  unsigned short* WoT = (unsigned short*)(ws + 19922944);    //  2,097,152 B
  unsigned short* Qp  = (unsigned short*)(ws + 22020096);    // 16,777,216 B
  unsigned short* Kp  = (unsigned short*)(ws + 38797312);    // 16,777,216 B
  unsigned short* Vt  = (unsigned short*)(ws + 55574528);    // 16,777,216 B
  unsigned short* Am  = (unsigned short*)(ws + 72351744);    //  8,388,608 B

  k_cvt_x<<<8192, 256, 0, stream>>>(x, x8);
  k_cvt_w<<<dim3(32, 32, 4), dim3(32, 8), 0, stream>>>(Wq, Wk, Wv, Wo, W8, WoT);
  k_gemm_qkv<<<dim3(8, 128, 3), 256, 0, stream>>>(x8, W8, bq, bk, bv, Qp, Kp, Vt);
  k_attn<<<dim3(8, 64), 512, 0, stream>>>(Qp, Kp, Vt, Am);
  k_gemm_out<<<dim3(8, 128), 256, 0, stream>>>(Am, WoT, bo, out);
}

// Round 17
// 308.682 us; speedup vs baseline: 1.0252x; 1.0252x over previous
//
#include <hip/hip_runtime.h>
#include <stdint.h>

typedef __attribute__((ext_vector_type(8))) __bf16 bf16x8;
typedef __attribute__((ext_vector_type(4))) float f32x4;
typedef __attribute__((ext_vector_type(8))) int i32x8;

#define DEV __device__ __forceinline__

DEV unsigned short f2bf(float f) {
  union { float f; uint32_t u; } v; v.f = f;
  return (unsigned short)((v.u + 0x7fffu + ((v.u >> 16) & 1u)) >> 16);
}

// pack two fp32 -> bf16 pair (round-half-up) in one v_perm (stable absmax floor)
DEV uint32_t pk2bf(float lo, float hi) {
  union { float f; uint32_t u; } a, b;
  a.f = lo; b.f = hi;
  return __builtin_amdgcn_perm(b.u + 0x8000u, a.u + 0x8000u, 0x07060302u);
}

DEV void gld16(const void* g, void* l) {
  __builtin_amdgcn_global_load_lds(
      (const __attribute__((address_space(1))) uint32_t*)g,
      (__attribute__((address_space(3))) uint32_t*)l, 16, 0, 0);
}

union Frag8 { i32x8 v; uint4 q[2]; };

// ---------------- convert x fp32 -> fp8 e4m3 (8 elems/thread) ----------------
__global__ __launch_bounds__(256) void k_cvt_x(const float* __restrict__ x,
                                               uint8_t* __restrict__ x8) {
  size_t t = (size_t)blockIdx.x * 256 + threadIdx.x;
  const float4* xv = (const float4*)x;
  float4 a = xv[t * 2], b = xv[t * 2 + 1];
  int lo = 0, hi = 0;
  lo = __builtin_amdgcn_cvt_pk_fp8_f32(a.x, a.y, lo, false);
  lo = __builtin_amdgcn_cvt_pk_fp8_f32(a.z, a.w, lo, true);
  hi = __builtin_amdgcn_cvt_pk_fp8_f32(b.x, b.y, hi, false);
  hi = __builtin_amdgcn_cvt_pk_fp8_f32(b.z, b.w, hi, true);
  int2 pk; pk.x = lo; pk.y = hi;
  *(int2*)&x8[t * 8] = pk;
}

// -------- weights: W[k][n] fp32 -> z<3: fp8 Wt[n][k] (x32); z=3: bf16 Wt[n][k] --------
__global__ void k_cvt_w(const float* __restrict__ W0, const float* __restrict__ W1,
                        const float* __restrict__ W2, const float* __restrict__ W3,
                        uint8_t* __restrict__ W8, unsigned short* __restrict__ WoT) {
  const int z = blockIdx.z;
  const float* W = (z == 0) ? W0 : (z == 1) ? W1 : (z == 2) ? W2 : W3;
  __shared__ float tile[32][33];
  const int n0 = blockIdx.x * 32, k0 = blockIdx.y * 32;
  const int tx = threadIdx.x, ty = threadIdx.y;
  const int tid = ty * 32 + tx;
#pragma unroll
  for (int i = 0; i < 4; i++)
    tile[ty * 4 + i][tx] = W[(size_t)(k0 + ty * 4 + i) * 1024 + n0 + tx];
  __syncthreads();
  if (z < 3) {
    int nn = tid >> 3, kg = tid & 7;  // tile[kk][nn] = W[k0+kk][n0+nn]
    int w_ = 0;
    w_ = __builtin_amdgcn_cvt_pk_fp8_f32(32.f * tile[kg * 4 + 0][nn],
                                         32.f * tile[kg * 4 + 1][nn], w_, false);
    w_ = __builtin_amdgcn_cvt_pk_fp8_f32(32.f * tile[kg * 4 + 2][nn],
                                         32.f * tile[kg * 4 + 3][nn], w_, true);
    *(uint32_t*)&W8[(size_t)z * 1048576 + (size_t)(n0 + nn) * 1024 + k0 + kg * 4] =
        (uint32_t)w_;
  } else {
#pragma unroll
    for (int i = 0; i < 4; i++)
      WoT[(size_t)(n0 + ty * 4 + i) * 1024 + k0 + tx] = f2bf(tile[tx][ty * 4 + i]);
  }
}

// ------- QKV projection: MX-fp8 128x128 tile, BK=128, K=1024, fused pool -------
// T4 counted-vmcnt sync + T5 setprio around MFMA cluster (R14/R15-verified).
// z=0 -> Qp [bh][s2][d] PRE-SCALED by 0.125*log2(e), z=1 -> Kp, z=2 -> Vt [bh][d][s2]
__global__ __launch_bounds__(256) void k_gemm_qkv(
    const uint8_t* __restrict__ A, const uint8_t* __restrict__ W8,
    const float* __restrict__ bq, const float* __restrict__ bk,
    const float* __restrict__ bv,
    unsigned short* __restrict__ Qp, unsigned short* __restrict__ Kp,
    unsigned short* __restrict__ Vt) {
  const int tid = threadIdx.x;
  int flat = (blockIdx.z * 128 + blockIdx.y) * 8 + blockIdx.x;
  int swz = (flat & 7) * 384 + (flat >> 3);   // XCD x owns swz in [x*384,(x+1)*384)
  const int n0 = (swz & 7) * 128;
  const int m0 = ((swz >> 3) & 127) * 128;
  const int z = swz >> 10;
  const uint8_t* Bt = W8 + (size_t)z * 1048576;
  const float* bias = (z == 0) ? bq : (z == 1) ? bk : bv;

  __shared__ __align__(16) uint8_t lA[2][16384];
  __shared__ __align__(16) uint8_t lB[2][16384];

  const int lane = tid & 63, w = tid >> 6;
  const int wr = w >> 1, wc = w & 1;
  const int r = lane & 15, qd = lane >> 4;
  const int rl = lane >> 3, sg = lane & 7;

  f32x4 acc[4][4];
#pragma unroll
  for (int i = 0; i < 4; i++)
#pragma unroll
    for (int j = 0; j < 4; j++) acc[i][j] = (f32x4){0.f, 0.f, 0.f, 0.f};

  // hoisted staging addresses (loop-invariant; K-offset folds into imm)
  const uint8_t* gA[4]; const uint8_t* gB[4]; uint32_t lo[4];
#pragma unroll
  for (int p = 0; p < 4; p++) {
    int row = (p * 4 + w) * 8 + rl;
    int g = sg ^ (row & 7);  // 16B-granule XOR swizzle (pre-swizzled global src)
    gA[p] = A + (size_t)(m0 + row) * 1024 + g * 16;
    gB[p] = Bt + (size_t)(n0 + row) * 1024 + g * 16;
    lo[p] = row * 128 + sg * 16;
  }

  // prologue: stage K-tile 0 into buffer 0 (8 loads in flight)
#pragma unroll
  for (int p = 0; p < 4; p++) {
    gld16(gA[p], &lA[0][lo[p]]);
    gld16(gB[p], &lB[0][lo[p]]);
  }

#pragma unroll
  for (int t = 0; t < 8; t++) {
    const int cb = t & 1;
    // 1) issue next tile's 8 loads (stay in flight across barrier)
    if (t < 7) {
#pragma unroll
      for (int p = 0; p < 4; p++) {
        gld16(gA[p] + (t + 1) * 128, &lA[cb ^ 1][lo[p]]);
        gld16(gB[p] + (t + 1) * 128, &lB[cb ^ 1][lo[p]]);
      }
      __builtin_amdgcn_sched_barrier(0);
      // wait only the PREVIOUS step's 8 loads (8 newest are next-tile's)
      asm volatile("s_waitcnt vmcnt(8)" ::: "memory");
    } else {
      asm volatile("s_waitcnt vmcnt(0)" ::: "memory");
    }
    __builtin_amdgcn_s_barrier();   // all waves: current buffer ready
    // 2) compute current buffer (prio 1: prefer MFMA-phase waves on the CU)
    __builtin_amdgcn_s_setprio(1);
    const uint8_t* lAc = lA[cb];
    const uint8_t* lBc = lB[cb];
    Frag8 bfr[4];
#pragma unroll
    for (int nt = 0; nt < 4; nt++) {
      int row = wc * 64 + nt * 16 + r;
      int g0 = (2 * qd) ^ (row & 7), g1 = (2 * qd + 1) ^ (row & 7);
      bfr[nt].q[0] = *(const uint4*)&lBc[row * 128 + g0 * 16];
      bfr[nt].q[1] = *(const uint4*)&lBc[row * 128 + g1 * 16];
    }
#pragma unroll
    for (int mt = 0; mt < 4; mt++) {
      int row = wr * 64 + mt * 16 + r;
      int g0 = (2 * qd) ^ (row & 7), g1 = (2 * qd + 1) ^ (row & 7);
      Frag8 af;
      af.q[0] = *(const uint4*)&lAc[row * 128 + g0 * 16];
      af.q[1] = *(const uint4*)&lAc[row * 128 + g1 * 16];
#pragma unroll
      for (int nt = 0; nt < 4; nt++)
        acc[mt][nt] = __builtin_amdgcn_mfma_scale_f32_16x16x128_f8f6f4(
            af.v, bfr[nt].v, acc[mt][nt], 0, 0, 0, 0x7f7f7f7f, 0, 0x7f7f7f7f);
    }
    __builtin_amdgcn_s_setprio(0);
    // 3) write-after-read guard before next step overwrites this buffer
    if (t < 7) __builtin_amdgcn_s_barrier();
  }

  unsigned short* OP = (z == 0) ? Qp : Kp;
  // fold softmax scale 0.125*log2(e) into Q (z==0); -0.5 shift dropped (cancels)
  const float K2 = 0.125f * 1.44269504f;
  const float osc = (z == 0) ? 0.03125f * K2 : 0.03125f;   // undo W x32, maybe *K2
  const float bsc = (z == 0) ? K2 : 1.f;
#pragma unroll
  for (int nt = 0; nt < 4; nt++) {
    int n = n0 + wc * 64 + nt * 16 + r;
    float bv_ = bias[n] * bsc;
    int h = n >> 6, d = n & 63;
#pragma unroll
    for (int mt = 0; mt < 4; mt++) {
      int mg = m0 + wr * 64 + mt * 16 + qd * 4;
      int b = mg >> 12, s2 = (mg & 4095) >> 1;
      int bh = b * 16 + h;
      f32x4 a = acc[mt][nt];
      float v0 = fmaxf(a.x, a.y) * osc + bv_;
      float v1 = fmaxf(a.z, a.w) * osc + bv_;
      if (z == 2) {
        uint32_t pk = (uint32_t)f2bf(v0) | ((uint32_t)f2bf(v1) << 16);
        *(uint32_t*)&Vt[((size_t)bh * 64 + d) * 2048 + s2] = pk;  // s2 even
      } else {
        size_t base = ((size_t)bh * 2048 + s2) * 64 + d;
        OP[base] = f2bf(v0);
        OP[base + 64] = f2bf(v1);
      }
    }
  }
}

// ---------------- final GEMM: out = Am(bf16) @ WoT^T + bo, fp32 out ----------------
// BM=32 tile -> 1024 blocks (4/CU by LDS 40KB and VGPR), acc 16 VGPR.
// T4 counted-vmcnt sync + T5 setprio (R15-verified).
__global__ __launch_bounds__(256) void k_gemm_out(
    const unsigned short* __restrict__ A, const unsigned short* __restrict__ Bt,
    const float* __restrict__ bias, float* __restrict__ fout) {
  const int tid = threadIdx.x;
  int flat = blockIdx.y * 8 + blockIdx.x;      // 1024 blocks = 8 XCDs x 128
  int swz = (flat & 7) * 128 + (flat >> 3);
  const int n0 = (swz & 7) * 128, m0 = (swz >> 3) * 32;

  __shared__ __align__(16) unsigned short lA[2][2048];   // 32 x 64
  __shared__ __align__(16) unsigned short lB[2][8192];   // 128 x 64

  const int lane = tid & 63, w = tid >> 6;
  const int wr = w >> 1, wc = w & 1;           // wave tile: 16 m x 64 n
  const int r = lane & 15, qd = lane >> 4;
  const int srow = tid >> 3, sg = tid & 7;     // srow 0..31

  f32x4 acc[4];
#pragma unroll
  for (int j = 0; j < 4; j++) acc[j] = (f32x4){0.f, 0.f, 0.f, 0.f};

  const unsigned short* gA; uint32_t loA;
  const unsigned short* gB[4]; uint32_t loB[4];
  {
    int row = srow;
    int gs = sg ^ (row & 7);
    gA = A + (size_t)(m0 + row) * 1024 + gs * 8;
    loA = row * 64 + sg * 8;
  }
#pragma unroll
  for (int p = 0; p < 4; p++) {
    int row = p * 32 + srow;
    int gs = sg ^ (row & 7);
    gB[p] = Bt + (size_t)(n0 + row) * 1024 + gs * 8;
    loB[p] = row * 64 + sg * 8;
  }

  gld16(gA, &lA[0][loA]);
#pragma unroll
  for (int p = 0; p < 4; p++) gld16(gB[p], &lB[0][loB[p]]);

#pragma unroll
  for (int t = 0; t < 16; t++) {
    const int cb = t & 1;
    if (t < 15) {
      gld16(gA + (t + 1) * 64, &lA[cb ^ 1][loA]);
#pragma unroll
      for (int p = 0; p < 4; p++) gld16(gB[p] + (t + 1) * 64, &lB[cb ^ 1][loB[p]]);
      __builtin_amdgcn_sched_barrier(0);
      asm volatile("s_waitcnt vmcnt(5)" ::: "memory");
    } else {
      asm volatile("s_waitcnt vmcnt(0)" ::: "memory");
    }
    __builtin_amdgcn_s_barrier();
    __builtin_amdgcn_s_setprio(1);
    const unsigned short* lAc = lA[cb];
    const unsigned short* lBc = lB[cb];
#pragma unroll
    for (int kf = 0; kf < 2; kf++) {
      bf16x8 af, bfr[4];
      {
        int row = wr * 16 + r;
        int lg = (kf * 4 + qd) ^ (row & 7);
        af = *(const bf16x8*)&lAc[row * 64 + lg * 8];
      }
#pragma unroll
      for (int nt = 0; nt < 4; nt++) {
        int row = wc * 64 + nt * 16 + r;
        int lg = (kf * 4 + qd) ^ (row & 7);
        bfr[nt] = *(const bf16x8*)&lBc[row * 64 + lg * 8];
      }
#pragma unroll
      for (int nt = 0; nt < 4; nt++)
        acc[nt] = __builtin_amdgcn_mfma_f32_16x16x32_bf16(af, bfr[nt],
                                                          acc[nt], 0, 0, 0);
    }
    __builtin_amdgcn_s_setprio(0);
    if (t < 15) __builtin_amdgcn_s_barrier();
  }

#pragma unroll
  for (int nt = 0; nt < 4; nt++) {
    int n = n0 + wc * 64 + nt * 16 + r;
    float bv = bias[n];
    int mg = m0 + wr * 16 + qd * 4;
    f32x4 a = acc[nt];
    fout[(size_t)(mg + 0) * 1024 + n] = a.x + bv;
    fout[(size_t)(mg + 1) * 1024 + n] = a.y + bv;
    fout[(size_t)(mg + 2) * 1024 + n] = a.z + bv;
    fout[(size_t)(mg + 3) * 1024 + n] = a.w + bv;
  }
}

// ---------------- flash attention (no-max softmax) + fused q-maxpool ----------------
// 8 warps x 32 q-rows (QBLK=256): K/V staging amortized over 8 warps; 16 waves/CU
// (2 blocks x 8, LDS 72KB). pk2bf (stable), T4 counted-vmcnt + T5 setprio
// (R15-verified: 310.0 us total, absmax exactly 0.015625).
__global__ __launch_bounds__(512) void k_attn(const unsigned short* __restrict__ Qp,
                                              const unsigned short* __restrict__ Kp,
                                              const unsigned short* __restrict__ Vt,
                                              unsigned short* __restrict__ Am) {
  const int tid = threadIdx.x;
  int flat = blockIdx.y * 8 + blockIdx.x;      // 512 blocks = 8 XCDs x 64
  int swz = (flat & 7) * 64 + (flat >> 3);
  const int qt = swz & 7, bh = swz >> 3;
  const int w = tid >> 6, lane = tid & 63;
  const int r = lane & 15, qd = lane >> 4;
  const int srow = tid >> 3, sg = tid & 7;     // srow 0..63

  __shared__ __align__(16) unsigned short lK[2][4096];
  __shared__ __align__(16) unsigned short lV[2][4096];
  __shared__ __align__(16) unsigned short lP[8][2][1280];

  const int q0 = qt * 256;
  const size_t qbase = ((size_t)bh * 2048 + q0 + w * 32 + r) * 64;
  bf16x8 bq0[2], bq1[2];
  bq0[0] = *(const bf16x8*)&Qp[qbase + qd * 8];
  bq1[0] = *(const bf16x8*)&Qp[qbase + 32 + qd * 8];
  bq0[1] = *(const bf16x8*)&Qp[qbase + 1024 + qd * 8];        // +16 q-rows
  bq1[1] = *(const bf16x8*)&Qp[qbase + 1024 + 32 + qd * 8];

  union { bf16x8 v; unsigned short u[8]; } onef;
#pragma unroll
  for (int j = 0; j < 8; j++) onef.u[j] = 0x3F80;  // bf16 1.0

  const unsigned short* Kg = Kp + (size_t)bh * 2048 * 64;
  const unsigned short* Vg = Vt + (size_t)bh * 64 * 2048;

  f32x4 accO[2][4]; f32x4 accS[2];
#pragma unroll
  for (int h = 0; h < 2; h++) {
    accS[h] = (f32x4){0.f, 0.f, 0.f, 0.f};
#pragma unroll
    for (int i = 0; i < 4; i++) accO[h][i] = (f32x4){0.f, 0.f, 0.f, 0.f};
  }

  char* lPw[2] = {(char*)&lP[w][0][0], (char*)&lP[w][1][0]};

  // hoisted staging addresses (64 rows covered by 512 threads: 1 K + 1 V each)
  const unsigned short* gK; const unsigned short* gV; uint32_t loKV;
  {
    int row = srow;
    int gs = sg ^ (row & 7);
    gK = Kg + (size_t)row * 64 + gs * 8;
    gV = Vg + (size_t)row * 2048 + gs * 8;
    loKV = row * 64 + sg * 8;
  }

  // prologue: stage K/V tile 0 into buffer 0 (2 loads in flight)
  gld16(gK, &lK[0][loKV]);
  gld16(gV, &lV[0][loKV]);

  for (int kb2 = 0; kb2 < 2048; kb2 += 128) {
#pragma unroll
    for (int ph = 0; ph < 2; ph++) {
      const int cb = ph;
      const int kn = kb2 + ph * 64 + 64;
      // prefetch next K/V tile (stays in flight across the barrier)
      if (kn < 2048) {
        gld16(gK + (size_t)kn * 64, &lK[cb ^ 1][loKV]);
        gld16(gV + kn, &lV[cb ^ 1][loKV]);
        __builtin_amdgcn_sched_barrier(0);
        asm volatile("s_waitcnt vmcnt(2)" ::: "memory");
      } else {
        asm volatile("s_waitcnt vmcnt(0)" ::: "memory");
      }
      __builtin_amdgcn_s_barrier();   // current K/V tile ready (all waves)

      const unsigned short* lKc = lK[cb];
      const unsigned short* lVc = lV[cb];

      // QK^T: read each K fragment ONCE, use for both q-halves
      __builtin_amdgcn_s_setprio(1);
      f32x4 s[2][4];
#pragma unroll
      for (int mt = 0; mt < 4; mt++) {
        int row = mt * 16 + r;
        int lg0 = qd ^ (row & 7), lg1 = (4 + qd) ^ (row & 7);
        bf16x8 ak0 = *(const bf16x8*)&lKc[row * 64 + lg0 * 8];
        bf16x8 ak1 = *(const bf16x8*)&lKc[row * 64 + lg1 * 8];
        f32x4 zz = (f32x4){0.f, 0.f, 0.f, 0.f};
        s[0][mt] = __builtin_amdgcn_mfma_f32_16x16x32_bf16(
            ak1, bq1[0],
            __builtin_amdgcn_mfma_f32_16x16x32_bf16(ak0, bq0[0], zz, 0, 0, 0),
            0, 0, 0);
        s[1][mt] = __builtin_amdgcn_mfma_f32_16x16x32_bf16(
            ak1, bq1[1],
            __builtin_amdgcn_mfma_f32_16x16x32_bf16(ak0, bq0[1], zz, 0, 0, 0),
            0, 0, 0);
      }
      __builtin_amdgcn_s_setprio(0);

      // p = exp2(s) (scale pre-folded into Q); pack via pk2bf (round-half-up)
#pragma unroll
      for (int h = 0; h < 2; h++)
#pragma unroll
        for (int mt = 0; mt < 4; mt++) {
          float p0 = __builtin_amdgcn_exp2f(s[h][mt][0]);
          float p1 = __builtin_amdgcn_exp2f(s[h][mt][1]);
          float p2 = __builtin_amdgcn_exp2f(s[h][mt][2]);
          float p3 = __builtin_amdgcn_exp2f(s[h][mt][3]);
          uint2 dw; dw.x = pk2bf(p0, p1); dw.y = pk2bf(p2, p3);
          int off = r * 160 + (((2 * mt + (qd >> 1)) ^ (r & 7)) << 4) + ((qd & 1) << 3);
          *(uint2*)(lPw[h] + off) = dw;
        }

      bf16x8 ap0[2], ap1[2];
      __builtin_amdgcn_s_setprio(1);
#pragma unroll
      for (int h = 0; h < 2; h++) {
        ap0[h] = *(const bf16x8*)(lPw[h] + r * 160 + ((qd ^ (r & 7)) << 4));
        ap1[h] = *(const bf16x8*)(lPw[h] + r * 160 + (((4 + qd) ^ (r & 7)) << 4));
        // row-sum on the matrix pipe (same C layout as accO)
        accS[h] = __builtin_amdgcn_mfma_f32_16x16x32_bf16(ap0[h], onef.v, accS[h], 0, 0, 0);
        accS[h] = __builtin_amdgcn_mfma_f32_16x16x32_bf16(ap1[h], onef.v, accS[h], 0, 0, 0);
      }

      // PV: read each V fragment ONCE, use for both q-halves
#pragma unroll
      for (int nt = 0; nt < 4; nt++) {
        int row = nt * 16 + r;
        int lg0 = qd ^ (row & 7), lg1 = (4 + qd) ^ (row & 7);
        bf16x8 bv0 = *(const bf16x8*)&lVc[row * 64 + lg0 * 8];
        bf16x8 bv1 = *(const bf16x8*)&lVc[row * 64 + lg1 * 8];
#pragma unroll
        for (int h = 0; h < 2; h++) {
          accO[h][nt] = __builtin_amdgcn_mfma_f32_16x16x32_bf16(ap0[h], bv0,
                                                               accO[h][nt], 0, 0, 0);
          accO[h][nt] = __builtin_amdgcn_mfma_f32_16x16x32_bf16(ap1[h], bv1,
                                                               accO[h][nt], 0, 0, 0);
        }
      }
      __builtin_amdgcn_s_setprio(0);
      __builtin_amdgcn_s_barrier();   // write-after-read guard
    }
  }

  // epilogue: divide by row-sums (accS has identical lane layout to accO) + q-maxpool
#pragma unroll
  for (int h = 0; h < 2; h++) {
    float i0 = 1.f / accS[h][0], i1 = 1.f / accS[h][1];
    float i2 = 1.f / accS[h][2], i3 = 1.f / accS[h][3];
    int q = q0 + w * 32 + h * 16 + qd * 4;
    int s4 = q >> 1;
#pragma unroll
    for (int nt = 0; nt < 4; nt++) {
      int d = nt * 16 + r;
      float o0 = fmaxf(accO[h][nt][0] * i0, accO[h][nt][1] * i1);
      float o1 = fmaxf(accO[h][nt][2] * i2, accO[h][nt][3] * i3);
      size_t base = ((size_t)bh * 1024 + s4) * 64 + d;
      Am[base] = f2bf(o0);
      Am[base + 64] = f2bf(o1);
    }
  }
}

extern "C" void kernel_launch(void* const* d_in, const int* in_sizes, int n_in,
                              void* d_out, int out_size, void* d_ws, size_t ws_size,
                              hipStream_t stream) {
  const float* x  = (const float*)d_in[0];
  const float* Wq = (const float*)d_in[1];
  const float* bq = (const float*)d_in[2];
  const float* Wk = (const float*)d_in[3];
  const float* bk = (const float*)d_in[4];
  const float* Wv = (const float*)d_in[5];
  const float* bv = (const float*)d_in[6];
  const float* Wo = (const float*)d_in[7];
  const float* bo = (const float*)d_in[8];
  float* out = (float*)d_out;

  uint8_t* ws = (uint8_t*)d_ws;
  uint8_t*        x8  = ws;                                  // 16,777,216 B
  uint8_t*        W8  = ws + 16777216;                       //  3,145,728 B
  unsigned short* WoT = (unsigned short*)(ws + 19922944);    //  2,097,152 B
  unsigned short* Qp  = (unsigned short*)(ws + 22020096);    // 16,777,216 B
  unsigned short* Kp  = (unsigned short*)(ws + 38797312);    // 16,777,216 B
  unsigned short* Vt  = (unsigned short*)(ws + 55574528);    // 16,777,216 B
  unsigned short* Am  = (unsigned short*)(ws + 72351744);    //  8,388,608 B

  k_cvt_x<<<8192, 256, 0, stream>>>(x, x8);
  k_cvt_w<<<dim3(32, 32, 4), dim3(32, 8), 0, stream>>>(Wq, Wk, Wv, Wo, W8, WoT);
  k_gemm_qkv<<<dim3(8, 128, 3), 256, 0, stream>>>(x8, W8, bq, bk, bv, Qp, Kp, Vt);
  k_attn<<<dim3(8, 64), 512, 0, stream>>>(Qp, Kp, Vt, Am);
  k_gemm_out<<<dim3(8, 128), 256, 0, stream>>>(Am, WoT, bo, out);
}